// Round 16
// baseline (176.481 us; speedup 1.0000x reference)
//
#include <hip/hip_runtime.h>
#include <hip/hip_bf16.h>

// BaggingMaxPool: out[d] = mean_k( max_{r in indices[k,:]} inp[r][d] )
// N=1024 rows, D=100000 cols, K=20 rounds, SELECT_N=256.
//
// Round-16: BF16 LDS tile. Tile[1024][16] in bf16 = 32 KB -> double-buffer
// + idx = 75.5 KB -> TWO blocks/CU (GRID=512, 10 waves = 5 waves/SIMD
// total): one block computes while the other drains (rounds 9/13 both hit
// ~116us with 1-effective-phase CUs). ds_read_b64 per entry-row halves DS
// tile-read time. Max math stays f32 (bf16->f32 = shift<<16, free).
// Staging: T14 issue-early global float4 -> regs (4/thread, +4 for
// tid<384), convert after compute, swizzled ds_write (slot = u^((r>>2)&3)
// -> conflict-free b64 reads; write+read both swizzled, gload_lds not used
// so no linear-dest constraint). One barrier per tile. Compute body =
// round-13's proven loop with inline entry addressing (no E[16] array ->
// lower VGPR) and DPP4/8 + shfl16/32 reduce.
// Precision: bf16 adds <=~1 ulp(2.2)=0.016 to absmax 0.0156; thr 0.076.

#define N_ROWS   1024
#define D_COLS   100000
#define K_ROUNDS 20
#define SEL_N    256
#define NIDX     (K_ROUNDS * SEL_N)         // 5120
#define CPB      16                         // cols per tile
#define ROWDW    8                          // dwords per bf16 row (16 cols)
#define NT       (D_COLS / CPB)             // 6250 tiles (exact)
#define BLOCK    640                        // 10 waves
#define GRID     512
#define WAVES    10
#define RNDS_PW  (K_ROUNDS / WAVES)         // 2
#define NEG_INF  (-3.402823466e+38f)

template<int CTRL>
__device__ __forceinline__ float dpp_shr_max(float x) {
    const int xi = __float_as_int(x);
    const int sh = __builtin_amdgcn_update_dpp(xi, xi, CTRL, 0xF, 0xF, false);
    return fmaxf(x, __int_as_float(sh));
}
#define ROW_SHR4 0x114
#define ROW_SHR8 0x118

__device__ __forceinline__ unsigned int pack_bf16(float a, float b) {
    __hip_bfloat162 h = __float22bfloat162_rn(make_float2(a, b));
    return *reinterpret_cast<unsigned int*>(&h);
}

// Convert 16 f32 cols -> bf16 row, write with unit-swizzle slot = u^sw(r).
__device__ __forceinline__ void write_row_bf16(unsigned int* tb, int row, const float4* p) {
    const int sw = (row >> 2) & 3;
    unsigned int* base = tb + row * ROWDW;
    #pragma unroll
    for (int u = 0; u < 4; ++u) {
        uint2 w;
        w.x = pack_bf16(p[u].x, p[u].y);
        w.y = pack_bf16(p[u].z, p[u].w);
        *reinterpret_cast<uint2*>(base + (((u ^ sw) << 1))) = w;
    }
}

__global__ __launch_bounds__(BLOCK, 5) void bagmax_kernel(
    const float* __restrict__ inp,
    const int*   __restrict__ indices,
    float*       __restrict__ out)
{
    __shared__ unsigned int tile[2][N_ROWS * ROWDW];        // 2 x 32 KB
    __shared__ __align__(16) unsigned short sidx[NIDX];     // 10.25 KB
    __shared__ float wpart[2][WAVES][CPB];                  // 1.25 KB

    const int tid  = threadIdx.x;
    const int lane = tid & 63;
    const int wave = tid >> 6;                               // 0..9

    // XCD-chunk swizzle (bijective on [0,512)): consecutive chunks same XCD.
    const int b   = blockIdx.x;
    const int swz = (b & 7) * 64 + (b >> 3);
    const int cnt = (NT - swz + GRID - 1) / GRID;           // 12 or 13 tiles

    // ---- idx preload: coalesced, u16 transposed to [k][g][j] ----
    for (int i = tid; i < NIDX; i += BLOCK) {
        const int p   = i & 255;
        const int dst = (i & ~255) | ((p & 15) << 4) | (p >> 4);
        sidx[dst] = (unsigned short)indices[i];
    }

    // ---- prologue: stage tile 0 (thread t -> row t; +row t+640 if t<384) ----
    {
        const int colb = swz * CPB;
        float4 p0[4], p1[4];
        const float4* g0 = reinterpret_cast<const float4*>(inp + (size_t)tid * D_COLS + colb);
        #pragma unroll
        for (int q = 0; q < 4; ++q) p0[q] = g0[q];
        if (tid < 384) {
            const float4* g1 = reinterpret_cast<const float4*>(inp + (size_t)(tid + 640) * D_COLS + colb);
            #pragma unroll
            for (int q = 0; q < 4; ++q) p1[q] = g1[q];
        }
        write_row_bf16(&tile[0][0], tid, p0);
        if (tid < 384) write_row_bf16(&tile[0][0], tid + 640, p1);
    }
    __syncthreads();

    const int g  = lane >> 2;            // entry group 0..15
    const int u2 = (lane & 3) << 1;      // col-unit dword offset (0,2,4,6)

    #pragma unroll 1
    for (int i = 0; i < cnt; ++i) {
        const int cur = i & 1;
        const bool havenext = (i + 1 < cnt);

        // ---- T14 issue-early: global f32 loads for tile i+1 into regs ----
        float4 p0[4], p1[4];
        if (havenext) {
            const int colb = (swz + (i + 1) * GRID) * CPB;
            const float4* g0 = reinterpret_cast<const float4*>(inp + (size_t)tid * D_COLS + colb);
            #pragma unroll
            for (int q = 0; q < 4; ++q) p0[q] = g0[q];
            if (tid < 384) {
                const float4* g1 = reinterpret_cast<const float4*>(inp + (size_t)(tid + 640) * D_COLS + colb);
                #pragma unroll
                for (int q = 0; q < 4; ++q) p1[q] = g1[q];
            }
        }

        // ---- finalize tile i-1 (other-parity wpart, stable since barrier) ----
        if (i > 0 && tid < CPB) {
            float s = 0.f;
            #pragma unroll
            for (int w = 0; w < WAVES; ++w) s += wpart[cur ^ 1][w][tid];
            out[(swz + (i - 1) * GRID) * CPB + tid] = s * (1.0f / (float)K_ROUNDS);
        }

        // ---- round-major compute on buf[cur]: wave owns rounds 2w,2w+1 ----
        const unsigned int* tb = &tile[cur][0];
        float4 rsum = make_float4(0.f, 0.f, 0.f, 0.f);
        #pragma unroll
        for (int kk = 0; kk < RNDS_PW; ++kk) {
            const int k = wave * RNDS_PW + kk;
            const uint4* sp = reinterpret_cast<const uint4*>(&sidx[k * SEL_N + g * 16]);
            const uint4 w0 = sp[0];
            const uint4 w1 = sp[1];

            float4 a0 = make_float4(NEG_INF, NEG_INF, NEG_INF, NEG_INF);
            float4 a1 = a0;
            // Each PROC handles the 2 entries packed in one u16x2 dword.
            // addr_dw = e*8 + sw(e)*2, sw(e)=(e>>2)&3; XOR in the unit (bits
            // disjoint): final = addr_dw ^ u2.
            #define PROC(dw) { \
                const unsigned int e0 = (dw) & 0xFFFFu, e1 = (dw) >> 16; \
                const uint2 v0 = *reinterpret_cast<const uint2*>( \
                    &tb[(((e0 << 3) | (((e0 >> 2) & 3u) << 1))) ^ u2]); \
                const uint2 v1 = *reinterpret_cast<const uint2*>( \
                    &tb[(((e1 << 3) | (((e1 >> 2) & 3u) << 1))) ^ u2]); \
                a0.x = fmaxf(a0.x, __uint_as_float(v0.x << 16)); \
                a0.y = fmaxf(a0.y, __uint_as_float(v0.x & 0xFFFF0000u)); \
                a0.z = fmaxf(a0.z, __uint_as_float(v0.y << 16)); \
                a0.w = fmaxf(a0.w, __uint_as_float(v0.y & 0xFFFF0000u)); \
                a1.x = fmaxf(a1.x, __uint_as_float(v1.x << 16)); \
                a1.y = fmaxf(a1.y, __uint_as_float(v1.x & 0xFFFF0000u)); \
                a1.z = fmaxf(a1.z, __uint_as_float(v1.y << 16)); \
                a1.w = fmaxf(a1.w, __uint_as_float(v1.y & 0xFFFF0000u)); \
            }
            PROC(w0.x) PROC(w0.y) PROC(w0.z) PROC(w0.w)
            PROC(w1.x) PROC(w1.y) PROC(w1.z) PROC(w1.w)
            #undef PROC

            float4 acc;
            acc.x = fmaxf(a0.x, a1.x); acc.y = fmaxf(a0.y, a1.y);
            acc.z = fmaxf(a0.z, a1.z); acc.w = fmaxf(a0.w, a1.w);

            // strides 4,8: DPP funnel (VALU) -> valid in lanes 12..15
            acc.x = dpp_shr_max<ROW_SHR4>(acc.x); acc.y = dpp_shr_max<ROW_SHR4>(acc.y);
            acc.z = dpp_shr_max<ROW_SHR4>(acc.z); acc.w = dpp_shr_max<ROW_SHR4>(acc.w);
            acc.x = dpp_shr_max<ROW_SHR8>(acc.x); acc.y = dpp_shr_max<ROW_SHR8>(acc.y);
            acc.z = dpp_shr_max<ROW_SHR8>(acc.z); acc.w = dpp_shr_max<ROW_SHR8>(acc.w);
            // strides 16,32: cross-row (DS pipe)
            acc.x = fmaxf(acc.x, __shfl_xor(acc.x, 16, 64));
            acc.y = fmaxf(acc.y, __shfl_xor(acc.y, 16, 64));
            acc.z = fmaxf(acc.z, __shfl_xor(acc.z, 16, 64));
            acc.w = fmaxf(acc.w, __shfl_xor(acc.w, 16, 64));
            acc.x = fmaxf(acc.x, __shfl_xor(acc.x, 32, 64));
            acc.y = fmaxf(acc.y, __shfl_xor(acc.y, 32, 64));
            acc.z = fmaxf(acc.z, __shfl_xor(acc.z, 32, 64));
            acc.w = fmaxf(acc.w, __shfl_xor(acc.w, 32, 64));

            rsum.x += acc.x; rsum.y += acc.y; rsum.z += acc.z; rsum.w += acc.w;
        }
        if (g == 3)   // lanes 12..15 hold the full reduction
            *reinterpret_cast<float4*>(&wpart[cur][wave][(lane & 3) * 4]) = rsum;

        // ---- convert + write prefetched tile into the other buffer ----
        if (havenext) {
            write_row_bf16(&tile[cur ^ 1][0], tid, p0);
            if (tid < 384) write_row_bf16(&tile[cur ^ 1][0], tid + 640, p1);
        }
        __syncthreads();
    }

    // ---- epilogue: finalize the last tile ----
    if (tid < CPB) {
        const int pb = (cnt - 1) & 1;
        float s = 0.f;
        #pragma unroll
        for (int w = 0; w < WAVES; ++w) s += wpart[pb][w][tid];
        out[(swz + (cnt - 1) * GRID) * CPB + tid] = s * (1.0f / (float)K_ROUNDS);
    }
}

extern "C" void kernel_launch(void* const* d_in, const int* in_sizes, int n_in,
                              void* d_out, int out_size, void* d_ws, size_t ws_size,
                              hipStream_t stream) {
    const float* inp     = (const float*)d_in[0];
    const int*   indices = (const int*)d_in[1];
    float*       out     = (float*)d_out;

    bagmax_kernel<<<GRID, BLOCK, 0, stream>>>(inp, indices, out);
}

// Round 17
// 138.734 us; speedup vs baseline: 1.2721x; 1.2721x over previous
//
#include <hip/hip_runtime.h>

// BaggingMaxPool: out[d] = mean_k( max_{r in indices[k,:]} inp[r][d] )
// N=1024 rows, D=100000 cols, K=20 rounds, SELECT_N=256.
//
// Round-17: ANTI-PHASED 2-blocks/CU. R9 (2 blocks/CU serial) = lockstep:
// HBM idles while all blocks compute -> 117us. R13 (1 block/CU async) =
// per-tile drain+barrier uncovered -> 115us. Here: single-buffered 64KB
// tile (+10.25KB idx = 74.8KB -> 2 blocks/CU, 20 waves/CU), serial
// stage->compute per block, and the CU's two blocks are forced half-period
// OUT OF PHASE: odd-partner blocks s_sleep ~2.7us once at launch. While
// block A computes (DS/VALU pipes), block B's gload_lds staging streams
// from HBM -> both resources continuously busy. Steady state: period
// ~5.2us serves 2 tiles/CU -> ~64us memory-bound target.
// Partner-parity predicate (b&1)^((b>>8)&1) anti-phases both plausible
// co-residency pairings: (2c,2c+1) and (c,c+256). Wrong pairing degrades
// to R9-lockstep (~117) - low downside, correctness unaffected.
// Staging/compute/idx-layout = R13 verbatim (proven, spill-free).

#define N_ROWS   1024
#define D_COLS   100000
#define K_ROUNDS 20
#define SEL_N    256
#define NIDX     (K_ROUNDS * SEL_N)         // 5120
#define CPB      16                         // cols per tile
#define NT       (D_COLS / CPB)             // 6250 tiles (exact)
#define BLOCK    640                        // 10 waves
#define GRID     512
#define WAVES    10
#define RNDS_PW  (K_ROUNDS / WAVES)         // 2
#define NEG_INF  (-3.402823466e+38f)

// acc = max(acc, lane_shifted_down_by_N) within each 16-lane row.
template<int CTRL>
__device__ __forceinline__ float dpp_shr_max(float x) {
    const int xi = __float_as_int(x);
    const int sh = __builtin_amdgcn_update_dpp(xi, xi, CTRL, 0xF, 0xF, false);
    return fmaxf(x, __int_as_float(sh));
}
#define ROW_SHR4 0x114
#define ROW_SHR8 0x118

__device__ __forceinline__ void async_cp16(const float* g, float* l) {
    __builtin_amdgcn_global_load_lds(
        (const __attribute__((address_space(1))) unsigned int*)g,
        (__attribute__((address_space(3))) unsigned int*)l,
        16, 0, 0);
}

// Waves 0..7 each stage 128 rows (8 x gload_lds of 16 rows x 16 cols).
// LDS dest wave-uniform (linear); HW adds lane*16B.
__device__ __forceinline__ void stage_tile(const float* __restrict__ inp,
                                           float* __restrict__ buf,
                                           int colbase, int wave, int lane) {
    if (wave < 8) {
        const int rsub = lane >> 2;             // 0..15
        const int c4   = (lane & 3) * 4;        // 0,4,8,12
        #pragma unroll
        for (int it = 0; it < 8; ++it) {
            const int row = wave * 128 + it * 16 + rsub;
            const float* g = inp + (size_t)row * D_COLS + colbase + c4;   // per-lane
            float* l = &buf[(wave * 128 + it * 16) * CPB];                // uniform
            async_cp16(g, l);
        }
    }
}

__global__ __launch_bounds__(BLOCK, 5) void bagmax_kernel(
    const float* __restrict__ inp,
    const int*   __restrict__ indices,
    float*       __restrict__ out)
{
    __shared__ float tile[N_ROWS * CPB];                    // 64 KB (single)
    __shared__ __align__(16) unsigned short sidx[NIDX];     // 10.25 KB
    __shared__ float wpart[WAVES][CPB];                     // 640 B

    const int tid  = threadIdx.x;
    const int lane = tid & 63;
    const int wave = tid >> 6;                               // 0..9
    const int b    = blockIdx.x;

    // ---- anti-phase: half-period sleep for one partner of each CU pair ----
    if (((b & 1) ^ ((b >> 8) & 1)) != 0)
        __builtin_amdgcn_s_sleep(100);                       // ~6400 cyc ~ 2.7us

    // XCD-chunk swizzle (bijective on [0,512)): consecutive chunks same XCD.
    const int swz = (b & 7) * 64 + (b >> 3);
    const int cnt = (NT - swz + GRID - 1) / GRID;           // 12 or 13 tiles

    // ---- idx preload: coalesced, u16 transposed to [k][g][j] ----
    for (int i = tid; i < NIDX; i += BLOCK) {
        const int p   = i & 255;
        const int dst = (i & ~255) | ((p & 15) << 4) | (p >> 4);
        sidx[dst] = (unsigned short)indices[i];
    }

    const int g = lane >> 2;            // entry group 0..15
    const int u = lane & 3;             // col unit (cols u*4..u*4+3)

    #pragma unroll 1
    for (int i = 0; i < cnt; ++i) {
        // ---- issue async staging of tile i (overwrites tile; prev compute
        //      finished at the barrier ending iteration i-1) ----
        stage_tile(inp, &tile[0], (swz + i * GRID) * CPB, wave, lane);

        // ---- finalize tile i-1 while the loads stream (wpart stable) ----
        if (i > 0 && tid < CPB) {
            float s = 0.f;
            #pragma unroll
            for (int w = 0; w < WAVES; ++w) s += wpart[w][tid];
            out[(swz + (i - 1) * GRID) * CPB + tid] = s * (1.0f / (float)K_ROUNDS);
        }

        // ---- drain + barrier: tile resident (also covers idx preload @i=0,
        //      and orders finalize-read of wpart before compute's writes) ----
        asm volatile("s_waitcnt vmcnt(0)" ::: "memory");
        __syncthreads();

        // ---- round-major compute: wave owns rounds 2w,2w+1 ----
        const float* tb = &tile[0];
        float4 rsum = make_float4(0.f, 0.f, 0.f, 0.f);
        #pragma unroll
        for (int kk = 0; kk < RNDS_PW; ++kk) {
            const int k = wave * RNDS_PW + kk;

            const uint4* sp = reinterpret_cast<const uint4*>(&sidx[k * SEL_N + g * 16]);
            const uint4 w0 = sp[0];
            const uint4 w1 = sp[1];
            unsigned int e[16];
            e[0]  = w0.x & 0xFFFFu; e[1]  = w0.x >> 16;
            e[2]  = w0.y & 0xFFFFu; e[3]  = w0.y >> 16;
            e[4]  = w0.z & 0xFFFFu; e[5]  = w0.z >> 16;
            e[6]  = w0.w & 0xFFFFu; e[7]  = w0.w >> 16;
            e[8]  = w1.x & 0xFFFFu; e[9]  = w1.x >> 16;
            e[10] = w1.y & 0xFFFFu; e[11] = w1.y >> 16;
            e[12] = w1.z & 0xFFFFu; e[13] = w1.z >> 16;
            e[14] = w1.w & 0xFFFFu; e[15] = w1.w >> 16;

            float4 a0 = make_float4(NEG_INF, NEG_INF, NEG_INF, NEG_INF);
            float4 a1 = a0;
            #pragma unroll
            for (int j = 0; j < 16; j += 2) {
                const float4 v0 = *reinterpret_cast<const float4*>(&tb[e[j]     * CPB + u * 4]);
                const float4 v1 = *reinterpret_cast<const float4*>(&tb[e[j + 1] * CPB + u * 4]);
                a0.x = fmaxf(a0.x, v0.x); a0.y = fmaxf(a0.y, v0.y);
                a0.z = fmaxf(a0.z, v0.z); a0.w = fmaxf(a0.w, v0.w);
                a1.x = fmaxf(a1.x, v1.x); a1.y = fmaxf(a1.y, v1.y);
                a1.z = fmaxf(a1.z, v1.z); a1.w = fmaxf(a1.w, v1.w);
            }
            float4 acc;
            acc.x = fmaxf(a0.x, a1.x); acc.y = fmaxf(a0.y, a1.y);
            acc.z = fmaxf(a0.z, a1.z); acc.w = fmaxf(a0.w, a1.w);

            // strides 4,8: DPP funnel (VALU pipe) -> valid in lanes 12..15
            acc.x = dpp_shr_max<ROW_SHR4>(acc.x); acc.y = dpp_shr_max<ROW_SHR4>(acc.y);
            acc.z = dpp_shr_max<ROW_SHR4>(acc.z); acc.w = dpp_shr_max<ROW_SHR4>(acc.w);
            acc.x = dpp_shr_max<ROW_SHR8>(acc.x); acc.y = dpp_shr_max<ROW_SHR8>(acc.y);
            acc.z = dpp_shr_max<ROW_SHR8>(acc.z); acc.w = dpp_shr_max<ROW_SHR8>(acc.w);
            // strides 16,32: cross-row (DS pipe)
            acc.x = fmaxf(acc.x, __shfl_xor(acc.x, 16, 64));
            acc.y = fmaxf(acc.y, __shfl_xor(acc.y, 16, 64));
            acc.z = fmaxf(acc.z, __shfl_xor(acc.z, 16, 64));
            acc.w = fmaxf(acc.w, __shfl_xor(acc.w, 16, 64));
            acc.x = fmaxf(acc.x, __shfl_xor(acc.x, 32, 64));
            acc.y = fmaxf(acc.y, __shfl_xor(acc.y, 32, 64));
            acc.z = fmaxf(acc.z, __shfl_xor(acc.z, 32, 64));
            acc.w = fmaxf(acc.w, __shfl_xor(acc.w, 32, 64));

            rsum.x += acc.x; rsum.y += acc.y; rsum.z += acc.z; rsum.w += acc.w;
        }
        if (g == 3)   // lanes 12..15 hold the full reduction; u = lane&3
            *reinterpret_cast<float4*>(&wpart[wave][u * 4]) = rsum;

        // ---- compute done: wpart ready, tile free for next stage ----
        __syncthreads();
    }

    // ---- epilogue: finalize the last tile ----
    if (tid < CPB) {
        float s = 0.f;
        #pragma unroll
        for (int w = 0; w < WAVES; ++w) s += wpart[w][tid];
        out[(swz + (cnt - 1) * GRID) * CPB + tid] = s * (1.0f / (float)K_ROUNDS);
    }
}

extern "C" void kernel_launch(void* const* d_in, const int* in_sizes, int n_in,
                              void* d_out, int out_size, void* d_ws, size_t ws_size,
                              hipStream_t stream) {
    const float* inp     = (const float*)d_in[0];
    const int*   indices = (const int*)d_in[1];
    float*       out     = (float*)d_out;

    bagmax_kernel<<<GRID, BLOCK, 0, stream>>>(inp, indices, out);
}